// Round 18
// baseline (3317.974 us; speedup 1.0000x reference)
//
#include <hip/hip_runtime.h>
#include <cstdint>
#include <cstddef>

#define S_LEN 1024
#define D_DIM 1024
#define NH 16
#define DHD 64
#define NL 8
#define FF_DIM 4096
#define HI_N 4
#define DI_N 64
#define TOPK_N 512
#define BSROWS 2048  // B * S
#define VOCAB 50257
#define VPAD 50304    // VOCAB rounded up to 128
#define NTILES_V 393  // ceil(50257/128)
#define YPX 50        // ceil(393/8) N-panels per XCD for logits

// compact QKV layout: [Q 0..1023 | K 1024..2047 | V 2048..3071], fp16
#define QKV_LD 3072
// indexer block layout (fp32): [QI 0..255 | KI 256..319 | WT 320..323 | pad..383]
#define IDX_LD 384
#define COL_QI 0
#define COL_KI 256
#define COL_WT 320

#define NEGF -3.0e38f

typedef __attribute__((ext_vector_type(8))) _Float16 half8;
typedef __attribute__((ext_vector_type(4))) _Float16 half4v;
typedef __attribute__((ext_vector_type(4))) float f32x4;

#if __has_builtin(__builtin_amdgcn_mfma_f32_16x16x16f16)
#define MFMA16F(a, b, c) __builtin_amdgcn_mfma_f32_16x16x16f16((a), (b), (c), 0, 0, 0)
#else
static __device__ __forceinline__ f32x4 mfma16f_asm(half4v a, half4v b, f32x4 c) {
  f32x4 d;
  asm volatile("v_mfma_f32_16x16x16_f16 %0, %1, %2, %3\n\ts_nop 7\n\ts_nop 7"
               : "=v"(d) : "v"(a), "v"(b), "v"(c));
  return d;
}
#define MFMA16F(a, b, c) mfma16f_asm((a), (b), (c))
#endif

// async global->LDS, 16B per lane; LDS dest must be lane-linear (rule #21)
typedef const __attribute__((address_space(1))) void* gas_ptr;
typedef __attribute__((address_space(3))) void* las_ptr;
__device__ __forceinline__ void gload16(const void* g, void* l) {
#if __has_builtin(__builtin_amdgcn_global_load_lds)
  __builtin_amdgcn_global_load_lds((gas_ptr)g, (las_ptr)l, 16, 0, 0);
#else
  *(uint4*)l = *(const uint4*)g;
#endif
}

__device__ __forceinline__ short f2h(float x) {  // RNE fp32->fp16 (bits)
  _Float16 h = (_Float16)x;
  return *reinterpret_cast<short*>(&h);
}
__device__ __forceinline__ float h2f(short b) {
  _Float16 h = *reinterpret_cast<_Float16*>(&b);
  return (float)h;
}
// two-term fp16 split: x ~= hi + lo with rel err ~2^-22
__device__ __forceinline__ void split_h(float x, short& hi, short& lo) {
  hi = f2h(x);
  lo = f2h(x - h2f(hi));
}

// ---------------- embed + positional ----------------
__global__ __launch_bounds__(256) void embed_kernel(
    const int* __restrict__ tokens, const float* __restrict__ E,
    const float* __restrict__ P, float* __restrict__ X)
{
  int bs = blockIdx.x;
  int s = bs & (S_LEN - 1);
  int tid = threadIdx.x;
  int tok = tokens[bs];
  float4 e = ((const float4*)(E + (size_t)tok * D_DIM))[tid];
  float4 p = ((const float4*)(P + (size_t)s * D_DIM))[tid];
  float4 o; o.x = e.x + p.x; o.y = e.y + p.y; o.z = e.z + p.z; o.w = e.w + p.w;
  ((float4*)(X + (size_t)bs * D_DIM))[tid] = o;
}

// ---------------- embed fp32 -> fp16, zero-padded to VPAD rows ----------------
__global__ __launch_bounds__(256) void cvt_embed_kernel(
    const float* __restrict__ E, short* __restrict__ Eh)
{
  const long valid4 = (long)VOCAB * D_DIM / 4;
  const long total4 = (long)VPAD * D_DIM / 4;
  long i = (long)blockIdx.x * 256 + threadIdx.x;
  long stride = (long)gridDim.x * 256;
  for (; i < total4; i += stride) {
    short4 o = make_short4(0, 0, 0, 0);
    if (i < valid4) {
      float4 v = ((const float4*)E)[i];
      o = make_short4(f2h(v.x), f2h(v.y), f2h(v.z), f2h(v.w));
    }
    ((short4*)Eh)[i] = o;
  }
}

// ---------------- rmsnorm -> split fp16 (hi plane, lo plane) ----------------
__global__ __launch_bounds__(256) void rmsnorm_split_kernel(
    const float* __restrict__ X, const float* __restrict__ W,
    short* __restrict__ O /* [2][BSROWS][D] */)
{
  int r = blockIdx.x;
  int tid = threadIdx.x;
  float4 v = ((const float4*)(X + (size_t)r * D_DIM))[tid];
  float ss = v.x * v.x + v.y * v.y + v.z * v.z + v.w * v.w;
  __shared__ float red[4];
  __shared__ float sh_inv;
  for (int o = 32; o; o >>= 1) ss += __shfl_down(ss, o);
  if ((tid & 63) == 0) red[tid >> 6] = ss;
  __syncthreads();
  if (tid == 0) {
    float s = red[0] + red[1] + red[2] + red[3];
    sh_inv = 1.0f / (sqrtf(s) * 0.03125f + 1e-6f);
  }
  __syncthreads();
  float inv = sh_inv;
  float4 w = ((const float4*)W)[tid];
  float o0 = w.x * v.x * inv, o1 = w.y * v.y * inv;
  float o2 = w.z * v.z * inv, o3 = w.w * v.w * inv;
  short4 hi, lo;
  split_h(o0, hi.x, lo.x); split_h(o1, hi.y, lo.y);
  split_h(o2, hi.z, lo.z); split_h(o3, hi.w, lo.w);
  ((short4*)(O + (size_t)r * D_DIM))[tid] = hi;
  ((short4*)(O + (size_t)BSROWS * D_DIM + (size_t)r * D_DIM))[tid] = lo;
}

// ---------------- rmsnorm -> plain fp16 ----------------
__global__ __launch_bounds__(256) void rmsnorm_h_kernel(
    const float* __restrict__ X, const float* __restrict__ W, short* __restrict__ O)
{
  int r = blockIdx.x;
  int tid = threadIdx.x;
  float4 v = ((const float4*)(X + (size_t)r * D_DIM))[tid];
  float ss = v.x * v.x + v.y * v.y + v.z * v.z + v.w * v.w;
  __shared__ float red[4];
  __shared__ float sh_inv;
  for (int o = 32; o; o >>= 1) ss += __shfl_down(ss, o);
  if ((tid & 63) == 0) red[tid >> 6] = ss;
  __syncthreads();
  if (tid == 0) {
    float s = red[0] + red[1] + red[2] + red[3];
    sh_inv = 1.0f / (sqrtf(s) * 0.03125f + 1e-6f);
  }
  __syncthreads();
  float inv = sh_inv;
  float4 w = ((const float4*)W)[tid];
  short4 o4 = make_short4(f2h(w.x * v.x * inv), f2h(w.y * v.y * inv),
                          f2h(w.z * v.z * inv), f2h(w.w * v.w * inv));
  ((short4*)(O + (size_t)r * D_DIM))[tid] = o4;
}

// ------- all-layer packs, float4-vectorized (grid.z = layer) -------
__global__ __launch_bounds__(256) void packT_all_kernel(
    const float* __restrict__ W0, short* __restrict__ BT0, int K, int N)
{
  __shared__ float t[32][132];
  int z = blockIdx.z;
  const float* W = W0 + (size_t)z * K * N;
  short* BT = BT0 + (size_t)z * N * K;
  int n0 = blockIdx.x * 128, k0 = blockIdx.y * 32;
  int tid = threadIdx.x;
#pragma unroll
  for (int f = 0; f < 4; ++f) {
    int idx = tid + f * 256;
    int k = idx >> 5, nv = idx & 31;
    float4 v = *(const float4*)(W + (size_t)(k0 + k) * N + n0 + nv * 4);
    *(float4*)&t[k][nv * 4] = v;
  }
  __syncthreads();
#pragma unroll
  for (int f = 0; f < 4; ++f) {
    int idx = tid + f * 256;
    int n = idx >> 3, kq = idx & 7;
    short4 o = make_short4(f2h(t[kq * 4 + 0][n]), f2h(t[kq * 4 + 1][n]),
                           f2h(t[kq * 4 + 2][n]), f2h(t[kq * 4 + 3][n]));
    *(short4*)(BT + (size_t)(n0 + n) * K + k0 + kq * 4) = o;
  }
}

__global__ __launch_bounds__(256) void pack_qkv_all_kernel(
    const float* __restrict__ wq0, const float* __restrict__ wk0,
    const float* __restrict__ wv0, short* __restrict__ BT0)
{
  __shared__ float t[32][132];
  int z = blockIdx.z;
  const float* wq = wq0 + (size_t)z * D_DIM * D_DIM;
  const float* wk = wk0 + (size_t)z * D_DIM * D_DIM;
  const float* wv = wv0 + (size_t)z * D_DIM * D_DIM;
  short* BT = BT0 + (size_t)z * QKV_LD * D_DIM;
  int n0 = blockIdx.x * 128, k0 = blockIdx.y * 32;
  int tid = threadIdx.x;
  const float* src = (n0 < 1024) ? wq : (n0 < 2048) ? wk : wv;
  int c0 = n0 & 1023;
#pragma unroll
  for (int f = 0; f < 4; ++f) {
    int idx = tid + f * 256;
    int k = idx >> 5, nv = idx & 31;
    float4 v = *(const float4*)(src + (size_t)(k0 + k) * 1024 + c0 + nv * 4);
    *(float4*)&t[k][nv * 4] = v;
  }
  __syncthreads();
#pragma unroll
  for (int f = 0; f < 4; ++f) {
    int idx = tid + f * 256;
    int n = idx >> 3, kq = idx & 7;
    short4 o = make_short4(f2h(t[kq * 4 + 0][n]), f2h(t[kq * 4 + 1][n]),
                           f2h(t[kq * 4 + 2][n]), f2h(t[kq * 4 + 3][n]));
    *(short4*)(BT + (size_t)(n0 + n) * D_DIM + k0 + kq * 4) = o;
  }
}

__global__ __launch_bounds__(256) void pack_idx_all_kernel(
    const float* __restrict__ iq0, const float* __restrict__ ik0,
    const float* __restrict__ iw0, short* __restrict__ BT0)
{
  __shared__ float t[32][33];
  const size_t plane = (size_t)IDX_LD * D_DIM;
  int z = blockIdx.z;
  const float* iq = iq0 + (size_t)z * D_DIM * (HI_N * DI_N);
  const float* ik = ik0 + (size_t)z * D_DIM * DI_N;
  const float* iw = iw0 + (size_t)z * D_DIM * HI_N;
  short* BT = BT0 + (size_t)z * 2 * plane;
  int n0 = blockIdx.x * 32, k0 = blockIdx.y * 32;
  int tx = threadIdx.x, ty = threadIdx.y;
  const float* src = nullptr; int ld = 0, c0 = 0;
  if (n0 < 256)      { src = iq; ld = 256; c0 = n0; }
  else if (n0 < 320) { src = ik; ld = 64;  c0 = n0 - 256; }
  else if (n0 < 352) { src = iw; ld = 4;   c0 = n0 - 320; }
#pragma unroll
  for (int r = 0; r < 32; r += 8) {
    float v = 0.f;
    int c = c0 + tx;
    if (src && c < ld) v = src[(size_t)(k0 + ty + r) * ld + c];
    t[ty + r][tx] = v;
  }
  __syncthreads();
#pragma unroll
  for (int r = 0; r < 32; r += 8) {
    short hi, lo;
    split_h(t[tx][ty + r], hi, lo);
    size_t o = (size_t)(n0 + ty + r) * D_DIM + k0 + tx;
    BT[o] = hi;
    BT[plane + o] = lo;
  }
}

#define RA 40  // padded LDS pitch for reg-staged split GEMM

// ------- split-fp16 GEMM (fp32-accurate), fp32 out: indexer only -------
template<int BM>
__global__ __launch_bounds__(256) void gemm_split_kernel(
    const short* __restrict__ A, size_t aplane,
    const short* __restrict__ BT, size_t bplane,
    float* __restrict__ C, int M, int N, int K)
{
  constexpr int MI = BM / 32;
  __shared__ short Al[2 * BM * RA];
  __shared__ short Bl[2 * 128 * RA];
  int tid = threadIdx.x;
  int wave = tid >> 6, lane = tid & 63;
  int wr = (wave >> 1) * (BM / 2), wc = (wave & 1) * 64;
  int lr = lane & 15, lk = lane >> 4;
  int m0 = blockIdx.y * BM, n0 = blockIdx.x * 128;
  f32x4 acc[MI][4] = {};

  for (int k0 = 0; k0 < K; k0 += 32) {
    __syncthreads();
#pragma unroll
    for (int f = 0; f < BM / 32; ++f) {
      int idx = tid + f * 256;
      int p = idx / (BM * 4), r2 = idx % (BM * 4);
      int row = r2 >> 2, sub = r2 & 3;
      uint4 v = *(const uint4*)(A + (size_t)p * aplane + (size_t)(m0 + row) * K + k0 + sub * 8);
      *(uint4*)(Al + p * BM * RA + row * RA + sub * 8) = v;
    }
#pragma unroll
    for (int f = 0; f < 4; ++f) {
      int idx = tid + f * 256;
      int p = idx >> 9, r2 = idx & 511;
      int row = r2 >> 2, sub = r2 & 3;
      uint4 v = *(const uint4*)(BT + (size_t)p * bplane + (size_t)(n0 + row) * K + k0 + sub * 8);
      *(uint4*)(Bl + p * 128 * RA + row * RA + sub * 8) = v;
    }
    __syncthreads();
    half8 ah[MI], al_[MI], bh[4], bl_[4];
#pragma unroll
    for (int i = 0; i < MI; ++i) {
      ah[i] = *(const half8*)(Al + (wr + i * 16 + lr) * RA + lk * 8);
      al_[i] = *(const half8*)(Al + BM * RA + (wr + i * 16 + lr) * RA + lk * 8);
    }
#pragma unroll
    for (int j = 0; j < 4; ++j) {
      bh[j] = *(const half8*)(Bl + (wc + j * 16 + lr) * RA + lk * 8);
      bl_[j] = *(const half8*)(Bl + 128 * RA + (wc + j * 16 + lr) * RA + lk * 8);
    }
#pragma unroll
    for (int i = 0; i < MI; ++i)
#pragma unroll
      for (int j = 0; j < 4; ++j) {
        f32x4 a = acc[i][j];
        a = __builtin_amdgcn_mfma_f32_16x16x32_f16(al_[i], bh[j], a, 0, 0, 0);
        a = __builtin_amdgcn_mfma_f32_16x16x32_f16(ah[i], bl_[j], a, 0, 0, 0);
        a = __builtin_amdgcn_mfma_f32_16x16x32_f16(ah[i], bh[j], a, 0, 0, 0);
        acc[i][j] = a;
      }
  }
#pragma unroll
  for (int i = 0; i < MI; ++i)
#pragma unroll
    for (int r = 0; r < 4; ++r) {
      int m = m0 + wr + i * 16 + lk * 4 + r;
#pragma unroll
      for (int j = 0; j < 4; ++j) {
        int n = n0 + wc + j * 16 + lr;
        if (n < N) C[(size_t)m * N + n] = acc[i][j][r];
      }
    }
}

// ------- plain fp16 GEMM: 2-phase double-buffered gload pipeline -------
// EPI: 1 fp16 store; 2 exact-GELU -> fp16 store; 3 fp32 + R
template<int BM, int EPI>
__global__ __launch_bounds__(256) void gemm_g_kernel(
    const short* __restrict__ A, const short* __restrict__ BT,
    const float* __restrict__ R, void* __restrict__ C, int M, int N, int K)
{
  constexpr int MI = BM / 32;
  constexpr int AF = (BM >= 64) ? BM / 64 : 1;
  __shared__ short Al[2][BM * 32];
  __shared__ short Bl[2][128 * 32];
  int tid = threadIdx.x;
  int wave = tid >> 6, lane = tid & 63;
  int wr = (wave >> 1) * (BM / 2), wc = (wave & 1) * 64;
  int lr = lane & 15, lk = lane >> 4;
  int m0 = blockIdx.y * BM, n0 = blockIdx.x * 128;
  f32x4 acc[MI][4] = {};

  const short* ap[AF]; int ad[AF];
#pragma unroll
  for (int f = 0; f < AF; ++f) {
    int idx = tid + f * 256;
    int row = idx >> 2, slot = idx & 3;
    ap[f] = A + (size_t)(m0 + row) * K + ((slot ^ (row & 3)) * 8);
    ad[f] = idx * 8;
  }
  const bool a_act = (BM >= 64) || (tid < BM * 4);
  const short* bp[2]; int bd[2];
#pragma unroll
  for (int f = 0; f < 2; ++f) {
    int idx = tid + f * 256;
    int row = idx >> 2, slot = idx & 3;
    bp[f] = BT + (size_t)(n0 + row) * K + ((slot ^ (row & 3)) * 8);
    bd[f] = idx * 8;
  }
  int aoff[MI], boff[4];
#pragma unroll
  for (int i = 0; i < MI; ++i) {
    int row = wr + i * 16 + lr;
    aoff[i] = row * 32 + ((lk ^ (row & 3)) * 8);
  }
#pragma unroll
  for (int j = 0; j < 4; ++j) {
    int row = wc + j * 16 + lr;
    boff[j] = row * 32 + ((lk ^ (row & 3)) * 8);
  }

#pragma unroll
  for (int f = 0; f < AF; ++f)
    if (a_act) { gload16(ap[f], &Al[0][ad[f]]); ap[f] += 32; }
#pragma unroll
  for (int f = 0; f < 2; ++f) { gload16(bp[f], &Bl[0][bd[f]]); bp[f] += 32; }
  __syncthreads();

  const int nt = K >> 5;
  int cur = 0;
  for (int t = 0; t < nt; ++t) {
    if (t + 1 < nt) {
#pragma unroll
      for (int f = 0; f < AF; ++f)
        if (a_act) { gload16(ap[f], &Al[cur ^ 1][ad[f]]); ap[f] += 32; }
#pragma unroll
      for (int f = 0; f < 2; ++f) { gload16(bp[f], &Bl[cur ^ 1][bd[f]]); bp[f] += 32; }
    }
    half8 af[MI], bfr[4];
#pragma unroll
    for (int i = 0; i < MI; ++i) af[i] = *(const half8*)(&Al[cur][aoff[i]]);
#pragma unroll
    for (int j = 0; j < 4; ++j) bfr[j] = *(const half8*)(&Bl[cur][boff[j]]);
#pragma unroll
    for (int i = 0; i < MI; ++i)
#pragma unroll
      for (int j = 0; j < 4; ++j)
        acc[i][j] = __builtin_amdgcn_mfma_f32_16x16x32_f16(af[i], bfr[j], acc[i][j], 0, 0, 0);
    __syncthreads();
    cur ^= 1;
  }
#pragma unroll
  for (int i = 0; i < MI; ++i)
#pragma unroll
    for (int r = 0; r < 4; ++r) {
      int m = m0 + wr + i * 16 + lk * 4 + r;
#pragma unroll
      for (int j = 0; j < 4; ++j) {
        int n = n0 + wc + j * 16 + lr;
        float v = acc[i][j][r];
        if (EPI == 1) {
          ((short*)C)[(size_t)m * N + n] = f2h(v);
        } else if (EPI == 2) {
          v = 0.5f * v * (1.0f + erff(v * 0.70710678118654752f));
          ((short*)C)[(size_t)m * N + n] = f2h(v);
        } else {
          ((float*)C)[(size_t)m * N + n] = v + R[(size_t)m * N + n];
        }
      }
    }
}

// ------- logits GEMM: 128x128, 2-phase dbuf gload pipeline + XCD 1D grid ------
__global__ __launch_bounds__(256) void gemm_logits_g_kernel(
    const short* __restrict__ A, const short* __restrict__ BT,
    float* __restrict__ C, int M, int N, int K)
{
  int bid = blockIdx.x;
  int xcd = bid & 7, idx0 = bid >> 3;
  int mt = idx0 & 15, yt = (idx0 >> 4) + xcd * YPX;
  if (yt >= NTILES_V) return;
  int m0 = mt * 128, n0 = yt * 128;

  __shared__ short Al[2][128 * 32];
  __shared__ short Bl[2][128 * 32];
  int tid = threadIdx.x;
  int wave = tid >> 6, lane = tid & 63;
  int wr = (wave >> 1) * 64, wc = (wave & 1) * 64;
  int lr = lane & 15, lk = lane >> 4;
  f32x4 acc[4][4] = {};

  const short* ap[2]; int ad[2];
  const short* bp[2]; int bd[2];
#pragma unroll
  for (int f = 0; f < 2; ++f) {
    int idx = tid + f * 256;
    int row = idx >> 2, slot = idx & 3;
    ap[f] = A + (size_t)(m0 + row) * K + ((slot ^ (row & 3)) * 8);
    ad[f] = idx * 8;
    bp[f] = BT + (size_t)(n0 + row) * K + ((slot ^ (row & 3)) * 8);
    bd[f] = idx * 8;
  }
  int aoff[4], boff[4];
#pragma unroll
  for (int i = 0; i < 4; ++i) {
    int row = wr + i * 16 + lr;
    aoff[i] = row * 32 + ((lk ^ (row & 3)) * 8);
    int rowb = wc + i * 16 + lr;
    boff[i] = rowb * 32 + ((lk ^ (rowb & 3)) * 8);
  }

#pragma unroll
  for (int f = 0; f < 2; ++f) { gload16(ap[f], &Al[0][ad[f]]); ap[f] += 32; }
#pragma unroll
  for (int f = 0; f < 2; ++f) { gload16(bp[f], &Bl[0][bd[f]]); bp[f] += 32; }
  __syncthreads();

  const int nt = K >> 5;
  int cur = 0;
  for (int t = 0; t < nt; ++t) {
    if (t + 1 < nt) {
#pragma unroll
      for (int f = 0; f < 2; ++f) { gload16(ap[f], &Al[cur ^ 1][ad[f]]); ap[f] += 32; }
#pragma unroll
      for (int f = 0; f < 2; ++f) { gload16(bp[f], &Bl[cur ^ 1][bd[f]]); bp[f] += 32; }
    }
    half8 af[4], bfr[4];
#pragma unroll
    for (int i = 0; i < 4; ++i) af[i] = *(const half8*)(&Al[cur][aoff[i]]);
#pragma unroll
    for (int j = 0; j < 4; ++j) bfr[j] = *(const half8*)(&Bl[cur][boff[j]]);
#pragma unroll
    for (int i = 0; i < 4; ++i)
#pragma unroll
      for (int j = 0; j < 4; ++j)
        acc[i][j] = __builtin_amdgcn_mfma_f32_16x16x32_f16(af[i], bfr[j], acc[i][j], 0, 0, 0);
    __syncthreads();
    cur ^= 1;
  }
#pragma unroll
  for (int i = 0; i < 4; ++i)
#pragma unroll
    for (int r = 0; r < 4; ++r) {
      int m = m0 + wr + i * 16 + lk * 4 + r;
#pragma unroll
      for (int j = 0; j < 4; ++j) {
        int n = n0 + wc + j * 16 + lr;
        if (n < N) C[(size_t)m * N + n] = acc[i][j][r];
      }
    }
}

// ------- logits fallback: B fp32 [N][K] inline-cvt (when ws too small) -------
__global__ __launch_bounds__(256) void gemm_logits_f32b_kernel(
    const short* __restrict__ A, const float* __restrict__ BT,
    float* __restrict__ C, int M, int N, int K)
{
  __shared__ short Al[128 * RA];
  __shared__ short Bl[128 * RA];
  int tid = threadIdx.x;
  int wave = tid >> 6, lane = tid & 63;
  int wr = (wave >> 1) * 64, wc = (wave & 1) * 64;
  int lr = lane & 15, lk = lane >> 4;
  int m0 = blockIdx.y * 128, n0 = blockIdx.x * 128;
  f32x4 acc[4][4] = {};

  for (int k0 = 0; k0 < K; k0 += 32) {
    __syncthreads();
#pragma unroll
    for (int f = 0; f < 2; ++f) {
      int idx = tid + f * 256, row = idx >> 2, sub = idx & 3;
      uint4 v = *(const uint4*)(A + (size_t)(m0 + row) * K + k0 + sub * 8);
      *(uint4*)(Al + row * RA + sub * 8) = v;
    }
#pragma unroll
    for (int f = 0; f < 4; ++f) {
      int idx = tid + f * 256, row = idx >> 3, qq = idx & 7;
      int gn = n0 + row;
      float4 v = make_float4(0.f, 0.f, 0.f, 0.f);
      if (gn < N) v = *(const float4*)(BT + (size_t)gn * K + k0 + qq * 4);
      *(short4*)(Bl + row * RA + qq * 4) =
          make_short4(f2h(v.x), f2h(v.y), f2h(v.z), f2h(v.w));
    }
    __syncthreads();
    half8 af[4], bfr[4];
#pragma unroll
    for (int i = 0; i < 4; ++i)
      af[i] = *(const half8*)(Al + (wr + i * 16 + lr) * RA + lk * 8);
#pragma unroll
    for (int j = 0; j < 4; ++j)
      bfr[j] = *(const half8*)(Bl + (wc + j * 16 + lr) * RA + lk * 8);
#pragma unroll
    for (int i = 0; i < 4; ++i)
#pragma unroll
      for (int j = 0; j < 4; ++j)
        acc[i][j] = __builtin_amdgcn_mfma_f32_16x16x32_f16(af[i], bfr[j], acc[i][j], 0, 0, 0);
  }
#pragma unroll
  for (int i = 0; i < 4; ++i)
#pragma unroll
    for (int r = 0; r < 4; ++r) {
      int m = m0 + wr + i * 16 + lk * 4 + r;
#pragma unroll
      for (int j = 0; j < 4; ++j) {
        int n = n0 + wc + j * 16 + lr;
        if (n < N) C[(size_t)m * N + n] = acc[i][j][r];
      }
    }
}

// ---------------- indexer scores + exact stable top-k -> bitmask ----------------
__device__ __forceinline__ unsigned int ford(float f) {
  unsigned int u = __float_as_uint(f);
  return (u & 0x80000000u) ? ~u : (u | 0x80000000u);
}

__global__ __launch_bounds__(256) void idx_topk_kernel(
    const float* __restrict__ Hx, unsigned int* __restrict__ MASK)
{
  int bq = blockIdx.x;
  int q = bq & (S_LEN - 1);
  int b = bq >> 10;
  int tid = threadIdx.x;
  int n = q + 1;
  if (n <= TOPK_N) {
    if (tid < 32) {
      int full = n >> 5, rem = n & 31;
      unsigned int w = 0u;
      if (tid < full) w = 0xFFFFFFFFu;
      else if (tid == full && rem) w = (1u << rem) - 1u;
      MASK[(size_t)bq * 32 + tid] = w;
    }
    return;
  }
  __shared__ float qi_s[HI_N * DI_N];
  __shared__ float wt_s[HI_N];
  __shared__ float sc[S_LEN];
  __shared__ unsigned long long keys[S_LEN];
  __shared__ unsigned int mw[32];
  qi_s[tid] = Hx[(size_t)bq * IDX_LD + COL_QI + tid];
  if (tid < HI_N) wt_s[tid] = Hx[(size_t)bq * IDX_LD + COL_WT + tid];
  __syncthreads();
  for (int k = tid; k < n; k += 256) {
    const float* kr = Hx + (size_t)(b * S_LEN + k) * IDX_LD + COL_KI;
    float d0 = 0.f, d1 = 0.f, d2 = 0.f, d3 = 0.f;
#pragma unroll
    for (int d = 0; d < DI_N; ++d) {
      float kv = kr[d];
      d0 = fmaf(qi_s[d], kv, d0);
      d1 = fmaf(qi_s[64 + d], kv, d1);
      d2 = fmaf(qi_s[128 + d], kv, d2);
      d3 = fmaf(qi_s[192 + d], kv, d3);
    }
    sc[k] = wt_s[0] * fmaxf(d0, 0.f) + wt_s[1] * fmaxf(d1, 0.f)
          + wt_s[2] * fmaxf(d2, 0.f) + wt_s[3] * fmaxf(d3, 0.f);
  }
  __syncthreads();
  for (int i = tid; i < S_LEN; i += 256) {
    unsigned long long kk = 0ull;
    if (i < n) kk = ((unsigned long long)ford(sc[i]) << 32) | (unsigned int)(S_LEN - 1 - i);
    keys[i] = kk;
  }
  __syncthreads();
  for (int size = 2; size <= S_LEN; size <<= 1) {
    for (int stride = size >> 1; stride > 0; stride >>= 1) {
      for (int t = tid; t < S_LEN / 2; t += 256) {
        int j = t & (stride - 1);
        int lo = ((t ^ j) << 1) | j;
        int hi = lo | stride;
        unsigned long long a = keys[lo], c = keys[hi];
        bool desc = ((lo & size) == 0);
        bool sw = desc ? (a < c) : (a > c);
        if (sw) { keys[lo] = c; keys[hi] = a; }
      }
      __syncthreads();
    }
  }
  if (tid < 32) mw[tid] = 0u;
  __syncthreads();
  for (int i = tid; i < TOPK_N; i += 256) {
    int k = S_LEN - 1 - (int)(keys[i] & 0xFFFFFFFFull);
    atomicOr(&mw[k >> 5], 1u << (k & 31));
  }
  __syncthreads();
  if (tid < 32) MASK[(size_t)bq * 32 + tid] = mw[tid];
}

// ------- split-K masked flash attention: each block handles a kt-range -------
// Grid 1024: part = i>>9, j = i&511 decoded as before (pair-balanced qt).
// Emits unnormalized O (fp32) + (m,l) per q-row; combine kernel merges parts.
__global__ __launch_bounds__(256) void attn_split_kernel(
    const short* __restrict__ QKV, const unsigned int* __restrict__ MASK,
    float* __restrict__ OP /* [2][BSROWS*NH][64] */,
    float2* __restrict__ ML /* [2][BSROWS*NH] */)
{
  __shared__ short Kl[2][64 * 64];
  __shared__ short Vtl[2][64 * 68];
  int i = blockIdx.x;
  int part = i >> 9;
  int j = i & 511;
  int p = j >> 5;
  int qt = (p < 8) ? p : 23 - p;
  int h = (j >> 1) & 15;
  int b = j & 1;
  int half_t = (qt + 2) >> 1;               // ceil((qt+1)/2)
  int kt_lo = part ? half_t : 0;
  int kt_hi = part ? (qt + 1) : half_t;
  int tid = threadIdx.x;
  int w = tid >> 6, l = tid & 63;
  int lq = l & 15, g = l >> 4;
  int q0 = qt * 64;
  const short* Kb = QKV + (size_t)b * S_LEN * QKV_LD + 1024 + h * DHD;
  const short* Vb = QKV + (size_t)b * S_LEN * QKV_LD + 2048 + h * DHD;
  int vu = tid >> 1, vhalf = tid & 1, vkg = vu >> 3, vdg = vu & 7;
  const int mrow = w * 16 + lq;
  const unsigned int* mp = MASK + (size_t)(b * S_LEN + q0 + mrow) * 32;

  f32x4 acc_o[4] = {};
  float m_run = -1.0e30f, l_run = 0.f;

  if (kt_lo < kt_hi) {
    half8 qf[2];
    {
      const short* qrow = QKV + ((size_t)(b * S_LEN + q0 + mrow)) * QKV_LD + h * DHD;
      qf[0] = *(const half8*)(qrow + g * 8);
      qf[1] = *(const half8*)(qrow + 32 + g * 8);
    }
    unsigned int mw0 = mp[2 * kt_lo], mw1 = mp[2 * kt_lo + 1];
    {
#pragma unroll
      for (int i2 = 0; i2 < 2; ++i2) {
        int idx = tid + i2 * 256;
        int row = idx >> 3, sub = idx & 7;
        gload16(Kb + (size_t)(kt_lo * 64 + row) * QKV_LD + (size_t)((sub ^ (row & 7)) * 8),
                &Kl[0][idx * 8]);
      }
      int krow = kt_lo * 64 + vkg * 4 + vhalf * 2;
      uint4 v0 = *(const uint4*)(Vb + (size_t)krow * QKV_LD + vdg * 8);
      uint4 v1 = *(const uint4*)(Vb + (size_t)(krow + 1) * QKV_LD + vdg * 8);
      const short* s0 = (const short*)&v0;
      const short* s1 = (const short*)&v1;
#pragma unroll
      for (int jj = 0; jj < 8; ++jj)
        *(short2*)(&Vtl[0][(vdg * 8 + jj) * 68 + vkg * 4 + vhalf * 2]) = make_short2(s0[jj], s1[jj]);
    }
    __syncthreads();

    int cur = 0;
    for (int kt = kt_lo; kt < kt_hi; ++kt) {
      bool more = kt + 1 < kt_hi;
      uint4 v0, v1;
      unsigned int nmw0 = 0u, nmw1 = 0u;
      if (more) {
#pragma unroll
        for (int i2 = 0; i2 < 2; ++i2) {
          int idx = tid + i2 * 256;
          int row = idx >> 3, sub = idx & 7;
          gload16(Kb + (size_t)((kt + 1) * 64 + row) * QKV_LD + (size_t)((sub ^ (row & 7)) * 8),
                  &Kl[cur ^ 1][idx * 8]);
        }
        int krow = (kt + 1) * 64 + vkg * 4 + vhalf * 2;
        v0 = *(const uint4*)(Vb + (size_t)krow * QKV_LD + vdg * 8);
        v1 = *(const uint4*)(Vb + (size_t)(krow + 1) * QKV_LD + vdg * 8);
        nmw0 = mp[2 * (kt + 1)];
        nmw1 = mp[2 * (kt + 1) + 1];
      }
      f32x4 s[4] = {};
      __builtin_amdgcn_s_setprio(1);
#pragma unroll
      for (int ks = 0; ks < 4; ++ks) {
        half8 kf0 = *(const half8*)(&Kl[cur][(ks * 16 + lq) * 64 + ((g ^ (lq & 7)) * 8)]);
        half8 kf1 = *(const half8*)(&Kl[cur][(ks * 16 + lq) * 64 + (((4 + g) ^ (lq & 7)) * 8)]);
        s[ks] = __builtin_amdgcn_mfma_f32_16x16x32_f16(kf0, qf[0], s[ks], 0, 0, 0);
        s[ks] = __builtin_amdgcn_mfma_f32_16x16x32_f16(kf1, qf[1], s[ks], 0, 0, 0);
      }
      __builtin_amdgcn_s_setprio(0);
      float mx = NEGF;
#pragma unroll
      for (int ks = 0; ks < 4; ++ks) {
        unsigned int mwv = (ks < 2) ? mw0 : mw1;
        int bb = (ks & 1) * 16 + g * 4;
#pragma unroll
        for (int r = 0; r < 4; ++r) {
          float sv = ((mwv >> (bb + r)) & 1u) ? s[ks][r] * 0.125f : NEGF;
          s[ks][r] = sv;
          mx = fmaxf(mx, sv);
        }
      }
      mx = fmaxf(mx, __shfl_xor(mx, 16));
      mx = fmaxf(mx, __shfl_xor(mx, 32));
      float m_new = fmaxf(m_run, mx);
      float scale = __expf(m_run - m_new);
      float lsum = 0.f;
      half4v pf[4];
#pragma unroll
      for (int ks = 0; ks < 4; ++ks) {
        half4v t;
#pragma unroll
        for (int r = 0; r < 4; ++r) {
          float pp = __expf(s[ks][r] - m_new);
          lsum += pp;
          t[r] = (_Float16)pp;
        }
        pf[ks] = t;
      }
      lsum += __shfl_xor(lsum, 16);
      lsum += __shfl_xor(lsum, 32);
      l_run = l_run * scale + lsum;
      m_run = m_new;
      float sc[4];
#pragma unroll
      for (int r = 0; r < 4; ++r) sc[r] = __shfl(scale, g * 4 + r);
      __builtin_amdgcn_s_setprio(1);
#pragma unroll
      for (int dt = 0; dt < 4; ++dt) {
        f32x4 a = acc_o[dt];
        a[0] *= sc[0]; a[1] *= sc[1]; a[2] *= sc[2]; a[3] *= sc[3];
#pragma unroll
        for (int ks = 0; ks < 4; ++ks) {
          half4v vf = *(const half4v*)(&Vtl[cur][(dt * 16 + lq) * 68 + ks * 16 + g * 4]);
          a = MFMA16F(pf[ks], vf, a);
        }
        acc_o[dt] = a;
      }
      __builtin_amdgcn_s_setprio(0);
      if (more) {
        const short* s0 = (const short*)&v0;
        const short* s1 = (const short*)&v1;
#pragma unroll
        for (int jj = 0; jj < 8; ++jj)
          *(short2*)(&Vtl[cur ^ 1][(vdg * 8 + jj) * 68 + vkg * 4 + vhalf * 2]) = make_short2(s0[jj], s1[jj]);
        mw0 = nmw0;
        mw1 = nmw1;
      }
      __syncthreads();
      cur ^= 1;
    }
  }
  // epilogue: unnormalized O + (m,l) partials
  const size_t opl = (size_t)BSROWS * NH * 64;
  float* op = OP + (size_t)part * opl;
#pragma unroll
  for (int dt = 0; dt < 4; ++dt)
#pragma unroll
    for (int r = 0; r < 4; ++r) {
      int q = q0 + w * 16 + g * 4 + r;
      op[((size_t)(b * S_LEN + q) * NH + h) * 64 + dt * 16 + lq] = acc_o[dt][r];
    }
  if (g == 0) {
    int q = q0 + mrow;
    ML[(size_t)part * BSROWS * NH + (size_t)(b * S_LEN + q) * NH + h] =
        make_float2(m_run, l_run);
  }
}

// ------- combine split-K attention partials -> fp16 AO -------
__global__ __launch_bounds__(256) void attn_combine_kernel(
    const float* __restrict__ OP, const float2* __restrict__ ML,
    short* __restrict__ AOh)
{
  int bq = blockIdx.x;
  int tid = threadIdx.x;
  const size_t opl = (size_t)BSROWS * NH * 64;
  const size_t mll = (size_t)BSROWS * NH;
#pragma unroll
  for (int f = 0; f < 4; ++f) {
    int idx = tid + f * 256;        // 0..1023 = h*64 + d
    int h = idx >> 6;
    float2 a = ML[(size_t)bq * NH + h];
    float2 c = ML[mll + (size_t)bq * NH + h];
    float m = fmaxf(a.x, c.x);
    float w0 = __expf(a.x - m), w1 = __expf(c.x - m);
    float den = a.y * w0 + c.y * w1;
    float o0 = OP[((size_t)bq * NH + h) * 64 + (idx & 63)];
    float o1 = OP[opl + ((size_t)bq * NH + h) * 64 + (idx & 63)];
    AOh[(size_t)bq * D_DIM + idx] = f2h((o0 * w0 + o1 * w1) / den);
  }
}

// ---------------- host orchestration ----------------
extern "C" void kernel_launch(void* const* d_in, const int* in_sizes, int n_in,
                              void* d_out, int out_size, void* d_ws, size_t ws_size,
                              hipStream_t stream) {
  (void)in_sizes; (void)n_in; (void)out_size;
  const int*   tokens  = (const int*)d_in[0];
  const float* embed_w = (const float*)d_in[1];
  const float* pos_w   = (const float*)d_in[2];
  const float* wq      = (const float*)d_in[3];
  const float* wk      = (const float*)d_in[4];
  const float* wv      = (const float*)d_in[5];
  const float* wo      = (const float*)d_in[6];
  const float* iqw     = (const float*)d_in[7];
  const float* ikw     = (const float*)d_in[8];
  const float* iww     = (const float*)d_in[9];
  const float* w1      = (const float*)d_in[10];
  const float* w2      = (const float*)d_in[11];
  const float* n1      = (const float*)d_in[12];
  const float* n2      = (const float*)d_in[13];
  const float* nf      = (const float*)d_in[14];
  float* logits = (float*)d_out;

  // ws: Hh (logits A, 4 MB) + Eh (fp16 embed padded to VPAD rows, 103 MB)
  short* Hh = (short*)d_ws;
  size_t need_eh = ((size_t)BSROWS * D_DIM + (size_t)VPAD * D_DIM) * 2;
  bool use_eh = ws_size >= need_eh;
  short* Eh = Hh + (size_t)BSROWS * D_DIM;

  // d_out scratch (all dead before logits GEMM writes)
  char* base = (char*)d_out;
  size_t off = (size_t)BSROWS * D_DIM * 4;
  float* X = logits;
  float* Hx = (float*)(base + off);    off += (size_t)BSROWS * IDX_LD * 4;
  short* QKVh = (short*)(base + off);  off += (size_t)BSROWS * QKV_LD * 2;
  short* Hsp = (short*)(base + off);   off += (size_t)2 * BSROWS * D_DIM * 2;
  short* AOh = (short*)(base + off);   off += (size_t)BSROWS * D_DIM * 2;
  short* FFh = (short*)(base + off);   off += (size_t)BSROWS * FF_DIM * 2;
  unsigned int* MASKb = (unsigned int*)(base + off); off += (size_t)BSROWS * 32 * 4;
  float* OPb = (float*)(base + off);   off += (size_t)2 * BSROWS * NH * 64 * 4;
  float2* MLb = (float2*)(base + off); off += (size_t)2 * BSROWS * NH * 8;
  short* BTqkvA = (short*)(base + off); off += (size_t)NL * QKV_LD * D_DIM * 2;
  short* BTidxA = (short*)(base + off); off += (size_t)NL * 2 * IDX_LD * D_DIM * 2;
  short* BTwoA = (short*)(base + off);  off += (size_t)NL * D_DIM * D_DIM * 2;
  short* BTw1A = (short*)(base + off);  off += (size_t)NL * FF_DIM * D_DIM * 2;
  short* BTw2A = (short*)(base + off);  off += (size_t)NL * FF_DIM * D_DIM * 2;

  const size_t plH  = (size_t)BSROWS * D_DIM;
  const size_t plIx = (size_t)IDX_LD * D_DIM;

  hipLaunchKernelGGL(embed_kernel, dim3(BSROWS), dim3(256), 0, stream,
                     tokens, embed_w, pos_w, X);
  if (use_eh)
    hipLaunchKernelGGL(cvt_embed_kernel, dim3(8192), dim3(256), 0, stream, embed_w, Eh);

  // all-layer weight packs (5 dispatches total, float4-vectorized)
  hipLaunchKernelGGL(pack_qkv_all_kernel, dim3(QKV_LD / 128, 32, NL), dim3(256), 0, stream,
                     wq, wk, wv, BTqkvA);
  hipLaunchKernelGGL(pack_idx_all_kernel, dim3(IDX_LD / 32, 32, NL), dim3(32, 8), 0, stream,
                     iqw, ikw, iww, BTidxA);
  hipLaunchKernelGGL(packT_all_kernel, dim3(D_DIM / 128, 32, NL), dim3(256), 0, stream,
                     wo, BTwoA, D_DIM, D_DIM);
  hipLaunchKernelGGL(packT_all_kernel, dim3(FF_DIM / 128, 32, NL), dim3(256), 0, stream,
                     w1, BTw1A, D_DIM, FF_DIM);
  hipLaunchKernelGGL(packT_all_kernel, dim3(D_DIM / 128, FF_DIM / 32, NL), dim3(256), 0, stream,
                     w2, BTw2A, FF_DIM, D_DIM);

  for (int l = 0; l < NL; ++l) {
    short* BTqkv = BTqkvA + (size_t)l * QKV_LD * D_DIM;
    short* BTidx = BTidxA + (size_t)l * 2 * IDX_LD * D_DIM;
    short* BTwo  = BTwoA + (size_t)l * D_DIM * D_DIM;
    short* BTw1  = BTw1A + (size_t)l * FF_DIM * D_DIM;
    short* BTw2  = BTw2A + (size_t)l * FF_DIM * D_DIM;

    hipLaunchKernelGGL(rmsnorm_split_kernel, dim3(BSROWS), dim3(256), 0, stream,
                       X, n1 + (size_t)l * D_DIM, Hsp);
    hipLaunchKernelGGL((gemm_g_kernel<64, 1>), dim3(QKV_LD / 128, 32), dim3(256), 0, stream,
                       Hsp, BTqkv, nullptr, QKVh, BSROWS, QKV_LD, D_DIM);
    hipLaunchKernelGGL((gemm_split_kernel<32>), dim3(IDX_LD / 128, 64), dim3(256), 0, stream,
                       Hsp, plH, BTidx, plIx, Hx, BSROWS, IDX_LD, D_DIM);
    hipLaunchKernelGGL(idx_topk_kernel, dim3(BSROWS), dim3(256), 0, stream, Hx, MASKb);
    hipLaunchKernelGGL(attn_split_kernel, dim3(1024), dim3(256), 0, stream,
                       QKVh, MASKb, OPb, MLb);
    hipLaunchKernelGGL(attn_combine_kernel, dim3(BSROWS), dim3(256), 0, stream,
                       OPb, MLb, AOh);
    hipLaunchKernelGGL((gemm_g_kernel<32, 3>), dim3(8, 64), dim3(256), 0, stream,
                       AOh, BTwo, X, X, BSROWS, D_DIM, D_DIM);
    hipLaunchKernelGGL(rmsnorm_h_kernel, dim3(BSROWS), dim3(256), 0, stream,
                       X, n2 + (size_t)l * D_DIM, Hsp);
    hipLaunchKernelGGL((gemm_g_kernel<64, 2>), dim3(FF_DIM / 128, 32), dim3(256), 0, stream,
                       Hsp, BTw1, nullptr, FFh, BSROWS, FF_DIM, D_DIM);
    hipLaunchKernelGGL((gemm_g_kernel<32, 3>), dim3(8, 64), dim3(256), 0, stream,
                       FFh, BTw2, X, X, BSROWS, D_DIM, FF_DIM);
  }

  hipLaunchKernelGGL(rmsnorm_h_kernel, dim3(BSROWS), dim3(256), 0, stream, X, nf, Hh);
  if (use_eh) {
    hipLaunchKernelGGL(gemm_logits_g_kernel, dim3(8 * YPX * 16), dim3(256), 0, stream,
                       Hh, Eh, logits, BSROWS, VOCAB, D_DIM);
  } else {
    hipLaunchKernelGGL(gemm_logits_f32b_kernel, dim3((VOCAB + 127) / 128, 16), dim3(256), 0, stream,
                       Hh, embed_w, logits, BSROWS, VOCAB, D_DIM);
  }
}

// Round 19
// 3227.473 us; speedup vs baseline: 1.0280x; 1.0280x over previous
//
#include <hip/hip_runtime.h>
#include <cstdint>
#include <cstddef>

#define S_LEN 1024
#define D_DIM 1024
#define NH 16
#define DHD 64
#define NL 8
#define FF_DIM 4096
#define HI_N 4
#define DI_N 64
#define TOPK_N 512
#define BSROWS 2048  // B * S
#define VOCAB 50257
#define VPAD 50304    // VOCAB rounded up to 128
#define NTILES_V 393  // ceil(50257/128)
#define YPX 50        // ceil(393/8) N-panels per XCD for logits

// compact QKV layout: [Q 0..1023 | K 1024..2047 | V 2048..3071], fp16
#define QKV_LD 3072
// indexer block layout (fp32): [QI 0..255 | KI 256..319 | WT 320..323 | pad..383]
#define IDX_LD 384
#define COL_QI 0
#define COL_KI 256
#define COL_WT 320

#define NEGF -3.0e38f

typedef __attribute__((ext_vector_type(8))) _Float16 half8;
typedef __attribute__((ext_vector_type(4))) _Float16 half4v;
typedef __attribute__((ext_vector_type(4))) float f32x4;

#if __has_builtin(__builtin_amdgcn_mfma_f32_16x16x16f16)
#define MFMA16F(a, b, c) __builtin_amdgcn_mfma_f32_16x16x16f16((a), (b), (c), 0, 0, 0)
#else
static __device__ __forceinline__ f32x4 mfma16f_asm(half4v a, half4v b, f32x4 c) {
  f32x4 d;
  asm volatile("v_mfma_f32_16x16x16_f16 %0, %1, %2, %3\n\ts_nop 7\n\ts_nop 7"
               : "=v"(d) : "v"(a), "v"(b), "v"(c));
  return d;
}
#define MFMA16F(a, b, c) mfma16f_asm((a), (b), (c))
#endif

// async global->LDS, 16B per lane; LDS dest must be lane-linear (rule #21)
typedef const __attribute__((address_space(1))) void* gas_ptr;
typedef __attribute__((address_space(3))) void* las_ptr;
__device__ __forceinline__ void gload16(const void* g, void* l) {
#if __has_builtin(__builtin_amdgcn_global_load_lds)
  __builtin_amdgcn_global_load_lds((gas_ptr)g, (las_ptr)l, 16, 0, 0);
#else
  *(uint4*)l = *(const uint4*)g;
#endif
}

__device__ __forceinline__ short f2h(float x) {  // RNE fp32->fp16 (bits)
  _Float16 h = (_Float16)x;
  return *reinterpret_cast<short*>(&h);
}
__device__ __forceinline__ float h2f(short b) {
  _Float16 h = *reinterpret_cast<_Float16*>(&b);
  return (float)h;
}
// two-term fp16 split: x ~= hi + lo with rel err ~2^-22
__device__ __forceinline__ void split_h(float x, short& hi, short& lo) {
  hi = f2h(x);
  lo = f2h(x - h2f(hi));
}

// ---------------- embed + positional ----------------
__global__ __launch_bounds__(256) void embed_kernel(
    const int* __restrict__ tokens, const float* __restrict__ E,
    const float* __restrict__ P, float* __restrict__ X)
{
  int bs = blockIdx.x;
  int s = bs & (S_LEN - 1);
  int tid = threadIdx.x;
  int tok = tokens[bs];
  float4 e = ((const float4*)(E + (size_t)tok * D_DIM))[tid];
  float4 p = ((const float4*)(P + (size_t)s * D_DIM))[tid];
  float4 o; o.x = e.x + p.x; o.y = e.y + p.y; o.z = e.z + p.z; o.w = e.w + p.w;
  ((float4*)(X + (size_t)bs * D_DIM))[tid] = o;
}

// ---------------- embed fp32 -> fp16, zero-padded to VPAD rows ----------------
__global__ __launch_bounds__(256) void cvt_embed_kernel(
    const float* __restrict__ E, short* __restrict__ Eh)
{
  const long valid4 = (long)VOCAB * D_DIM / 4;
  const long total4 = (long)VPAD * D_DIM / 4;
  long i = (long)blockIdx.x * 256 + threadIdx.x;
  long stride = (long)gridDim.x * 256;
  for (; i < total4; i += stride) {
    short4 o = make_short4(0, 0, 0, 0);
    if (i < valid4) {
      float4 v = ((const float4*)E)[i];
      o = make_short4(f2h(v.x), f2h(v.y), f2h(v.z), f2h(v.w));
    }
    ((short4*)Eh)[i] = o;
  }
}

// ---------------- rmsnorm -> split fp16 (hi plane, lo plane) ----------------
__global__ __launch_bounds__(256) void rmsnorm_split_kernel(
    const float* __restrict__ X, const float* __restrict__ W,
    short* __restrict__ O /* [2][BSROWS][D] */)
{
  int r = blockIdx.x;
  int tid = threadIdx.x;
  float4 v = ((const float4*)(X + (size_t)r * D_DIM))[tid];
  float ss = v.x * v.x + v.y * v.y + v.z * v.z + v.w * v.w;
  __shared__ float red[4];
  __shared__ float sh_inv;
  for (int o = 32; o; o >>= 1) ss += __shfl_down(ss, o);
  if ((tid & 63) == 0) red[tid >> 6] = ss;
  __syncthreads();
  if (tid == 0) {
    float s = red[0] + red[1] + red[2] + red[3];
    sh_inv = 1.0f / (sqrtf(s) * 0.03125f + 1e-6f);
  }
  __syncthreads();
  float inv = sh_inv;
  float4 w = ((const float4*)W)[tid];
  float o0 = w.x * v.x * inv, o1 = w.y * v.y * inv;
  float o2 = w.z * v.z * inv, o3 = w.w * v.w * inv;
  short4 hi, lo;
  split_h(o0, hi.x, lo.x); split_h(o1, hi.y, lo.y);
  split_h(o2, hi.z, lo.z); split_h(o3, hi.w, lo.w);
  ((short4*)(O + (size_t)r * D_DIM))[tid] = hi;
  ((short4*)(O + (size_t)BSROWS * D_DIM + (size_t)r * D_DIM))[tid] = lo;
}

// ---------------- rmsnorm -> plain fp16 ----------------
__global__ __launch_bounds__(256) void rmsnorm_h_kernel(
    const float* __restrict__ X, const float* __restrict__ W, short* __restrict__ O)
{
  int r = blockIdx.x;
  int tid = threadIdx.x;
  float4 v = ((const float4*)(X + (size_t)r * D_DIM))[tid];
  float ss = v.x * v.x + v.y * v.y + v.z * v.z + v.w * v.w;
  __shared__ float red[4];
  __shared__ float sh_inv;
  for (int o = 32; o; o >>= 1) ss += __shfl_down(ss, o);
  if ((tid & 63) == 0) red[tid >> 6] = ss;
  __syncthreads();
  if (tid == 0) {
    float s = red[0] + red[1] + red[2] + red[3];
    sh_inv = 1.0f / (sqrtf(s) * 0.03125f + 1e-6f);
  }
  __syncthreads();
  float inv = sh_inv;
  float4 w = ((const float4*)W)[tid];
  short4 o4 = make_short4(f2h(w.x * v.x * inv), f2h(w.y * v.y * inv),
                          f2h(w.z * v.z * inv), f2h(w.w * v.w * inv));
  ((short4*)(O + (size_t)r * D_DIM))[tid] = o4;
}

// ------- all-layer packs, float4-vectorized (grid.z = layer) -------
__global__ __launch_bounds__(256) void packT_all_kernel(
    const float* __restrict__ W0, short* __restrict__ BT0, int K, int N)
{
  __shared__ float t[32][132];
  int z = blockIdx.z;
  const float* W = W0 + (size_t)z * K * N;
  short* BT = BT0 + (size_t)z * N * K;
  int n0 = blockIdx.x * 128, k0 = blockIdx.y * 32;
  int tid = threadIdx.x;
#pragma unroll
  for (int f = 0; f < 4; ++f) {
    int idx = tid + f * 256;
    int k = idx >> 5, nv = idx & 31;
    float4 v = *(const float4*)(W + (size_t)(k0 + k) * N + n0 + nv * 4);
    *(float4*)&t[k][nv * 4] = v;
  }
  __syncthreads();
#pragma unroll
  for (int f = 0; f < 4; ++f) {
    int idx = tid + f * 256;
    int n = idx >> 3, kq = idx & 7;
    short4 o = make_short4(f2h(t[kq * 4 + 0][n]), f2h(t[kq * 4 + 1][n]),
                           f2h(t[kq * 4 + 2][n]), f2h(t[kq * 4 + 3][n]));
    *(short4*)(BT + (size_t)(n0 + n) * K + k0 + kq * 4) = o;
  }
}

__global__ __launch_bounds__(256) void pack_qkv_all_kernel(
    const float* __restrict__ wq0, const float* __restrict__ wk0,
    const float* __restrict__ wv0, short* __restrict__ BT0)
{
  __shared__ float t[32][132];
  int z = blockIdx.z;
  const float* wq = wq0 + (size_t)z * D_DIM * D_DIM;
  const float* wk = wk0 + (size_t)z * D_DIM * D_DIM;
  const float* wv = wv0 + (size_t)z * D_DIM * D_DIM;
  short* BT = BT0 + (size_t)z * QKV_LD * D_DIM;
  int n0 = blockIdx.x * 128, k0 = blockIdx.y * 32;
  int tid = threadIdx.x;
  const float* src = (n0 < 1024) ? wq : (n0 < 2048) ? wk : wv;
  int c0 = n0 & 1023;
#pragma unroll
  for (int f = 0; f < 4; ++f) {
    int idx = tid + f * 256;
    int k = idx >> 5, nv = idx & 31;
    float4 v = *(const float4*)(src + (size_t)(k0 + k) * 1024 + c0 + nv * 4);
    *(float4*)&t[k][nv * 4] = v;
  }
  __syncthreads();
#pragma unroll
  for (int f = 0; f < 4; ++f) {
    int idx = tid + f * 256;
    int n = idx >> 3, kq = idx & 7;
    short4 o = make_short4(f2h(t[kq * 4 + 0][n]), f2h(t[kq * 4 + 1][n]),
                           f2h(t[kq * 4 + 2][n]), f2h(t[kq * 4 + 3][n]));
    *(short4*)(BT + (size_t)(n0 + n) * D_DIM + k0 + kq * 4) = o;
  }
}

__global__ __launch_bounds__(256) void pack_idx_all_kernel(
    const float* __restrict__ iq0, const float* __restrict__ ik0,
    const float* __restrict__ iw0, short* __restrict__ BT0)
{
  __shared__ float t[32][33];
  const size_t plane = (size_t)IDX_LD * D_DIM;
  int z = blockIdx.z;
  const float* iq = iq0 + (size_t)z * D_DIM * (HI_N * DI_N);
  const float* ik = ik0 + (size_t)z * D_DIM * DI_N;
  const float* iw = iw0 + (size_t)z * D_DIM * HI_N;
  short* BT = BT0 + (size_t)z * 2 * plane;
  int n0 = blockIdx.x * 32, k0 = blockIdx.y * 32;
  int tx = threadIdx.x, ty = threadIdx.y;
  const float* src = nullptr; int ld = 0, c0 = 0;
  if (n0 < 256)      { src = iq; ld = 256; c0 = n0; }
  else if (n0 < 320) { src = ik; ld = 64;  c0 = n0 - 256; }
  else if (n0 < 352) { src = iw; ld = 4;   c0 = n0 - 320; }
#pragma unroll
  for (int r = 0; r < 32; r += 8) {
    float v = 0.f;
    int c = c0 + tx;
    if (src && c < ld) v = src[(size_t)(k0 + ty + r) * ld + c];
    t[ty + r][tx] = v;
  }
  __syncthreads();
#pragma unroll
  for (int r = 0; r < 32; r += 8) {
    short hi, lo;
    split_h(t[tx][ty + r], hi, lo);
    size_t o = (size_t)(n0 + ty + r) * D_DIM + k0 + tx;
    BT[o] = hi;
    BT[plane + o] = lo;
  }
}

#define RA 40  // padded LDS pitch for reg-staged split GEMM

// ------- split-fp16 GEMM (fp32-accurate), fp32 out: indexer only -------
template<int BM>
__global__ __launch_bounds__(256) void gemm_split_kernel(
    const short* __restrict__ A, size_t aplane,
    const short* __restrict__ BT, size_t bplane,
    float* __restrict__ C, int M, int N, int K)
{
  constexpr int MI = BM / 32;
  __shared__ short Al[2 * BM * RA];
  __shared__ short Bl[2 * 128 * RA];
  int tid = threadIdx.x;
  int wave = tid >> 6, lane = tid & 63;
  int wr = (wave >> 1) * (BM / 2), wc = (wave & 1) * 64;
  int lr = lane & 15, lk = lane >> 4;
  int m0 = blockIdx.y * BM, n0 = blockIdx.x * 128;
  f32x4 acc[MI][4] = {};

  for (int k0 = 0; k0 < K; k0 += 32) {
    __syncthreads();
#pragma unroll
    for (int f = 0; f < BM / 32; ++f) {
      int idx = tid + f * 256;
      int p = idx / (BM * 4), r2 = idx % (BM * 4);
      int row = r2 >> 2, sub = r2 & 3;
      uint4 v = *(const uint4*)(A + (size_t)p * aplane + (size_t)(m0 + row) * K + k0 + sub * 8);
      *(uint4*)(Al + p * BM * RA + row * RA + sub * 8) = v;
    }
#pragma unroll
    for (int f = 0; f < 4; ++f) {
      int idx = tid + f * 256;
      int p = idx >> 9, r2 = idx & 511;
      int row = r2 >> 2, sub = r2 & 3;
      uint4 v = *(const uint4*)(BT + (size_t)p * bplane + (size_t)(n0 + row) * K + k0 + sub * 8);
      *(uint4*)(Bl + p * 128 * RA + row * RA + sub * 8) = v;
    }
    __syncthreads();
    half8 ah[MI], al_[MI], bh[4], bl_[4];
#pragma unroll
    for (int i = 0; i < MI; ++i) {
      ah[i] = *(const half8*)(Al + (wr + i * 16 + lr) * RA + lk * 8);
      al_[i] = *(const half8*)(Al + BM * RA + (wr + i * 16 + lr) * RA + lk * 8);
    }
#pragma unroll
    for (int j = 0; j < 4; ++j) {
      bh[j] = *(const half8*)(Bl + (wc + j * 16 + lr) * RA + lk * 8);
      bl_[j] = *(const half8*)(Bl + 128 * RA + (wc + j * 16 + lr) * RA + lk * 8);
    }
#pragma unroll
    for (int i = 0; i < MI; ++i)
#pragma unroll
      for (int j = 0; j < 4; ++j) {
        f32x4 a = acc[i][j];
        a = __builtin_amdgcn_mfma_f32_16x16x32_f16(al_[i], bh[j], a, 0, 0, 0);
        a = __builtin_amdgcn_mfma_f32_16x16x32_f16(ah[i], bl_[j], a, 0, 0, 0);
        a = __builtin_amdgcn_mfma_f32_16x16x32_f16(ah[i], bh[j], a, 0, 0, 0);
        acc[i][j] = a;
      }
  }
#pragma unroll
  for (int i = 0; i < MI; ++i)
#pragma unroll
    for (int r = 0; r < 4; ++r) {
      int m = m0 + wr + i * 16 + lk * 4 + r;
#pragma unroll
      for (int j = 0; j < 4; ++j) {
        int n = n0 + wc + j * 16 + lr;
        if (n < N) C[(size_t)m * N + n] = acc[i][j][r];
      }
    }
}

// ------- plain fp16 GEMM: 2-phase double-buffered gload pipeline -------
// EPI: 1 fp16 store; 2 exact-GELU -> fp16 store; 3 fp32 + R
template<int BM, int EPI>
__global__ __launch_bounds__(256) void gemm_g_kernel(
    const short* __restrict__ A, const short* __restrict__ BT,
    const float* __restrict__ R, void* __restrict__ C, int M, int N, int K)
{
  constexpr int MI = BM / 32;
  constexpr int AF = (BM >= 64) ? BM / 64 : 1;
  __shared__ short Al[2][BM * 32];
  __shared__ short Bl[2][128 * 32];
  int tid = threadIdx.x;
  int wave = tid >> 6, lane = tid & 63;
  int wr = (wave >> 1) * (BM / 2), wc = (wave & 1) * 64;
  int lr = lane & 15, lk = lane >> 4;
  int m0 = blockIdx.y * BM, n0 = blockIdx.x * 128;
  f32x4 acc[MI][4] = {};

  const short* ap[AF]; int ad[AF];
#pragma unroll
  for (int f = 0; f < AF; ++f) {
    int idx = tid + f * 256;
    int row = idx >> 2, slot = idx & 3;
    ap[f] = A + (size_t)(m0 + row) * K + ((slot ^ (row & 3)) * 8);
    ad[f] = idx * 8;
  }
  const bool a_act = (BM >= 64) || (tid < BM * 4);
  const short* bp[2]; int bd[2];
#pragma unroll
  for (int f = 0; f < 2; ++f) {
    int idx = tid + f * 256;
    int row = idx >> 2, slot = idx & 3;
    bp[f] = BT + (size_t)(n0 + row) * K + ((slot ^ (row & 3)) * 8);
    bd[f] = idx * 8;
  }
  int aoff[MI], boff[4];
#pragma unroll
  for (int i = 0; i < MI; ++i) {
    int row = wr + i * 16 + lr;
    aoff[i] = row * 32 + ((lk ^ (row & 3)) * 8);
  }
#pragma unroll
  for (int j = 0; j < 4; ++j) {
    int row = wc + j * 16 + lr;
    boff[j] = row * 32 + ((lk ^ (row & 3)) * 8);
  }

#pragma unroll
  for (int f = 0; f < AF; ++f)
    if (a_act) { gload16(ap[f], &Al[0][ad[f]]); ap[f] += 32; }
#pragma unroll
  for (int f = 0; f < 2; ++f) { gload16(bp[f], &Bl[0][bd[f]]); bp[f] += 32; }
  __syncthreads();

  const int nt = K >> 5;
  int cur = 0;
  for (int t = 0; t < nt; ++t) {
    if (t + 1 < nt) {
#pragma unroll
      for (int f = 0; f < AF; ++f)
        if (a_act) { gload16(ap[f], &Al[cur ^ 1][ad[f]]); ap[f] += 32; }
#pragma unroll
      for (int f = 0; f < 2; ++f) { gload16(bp[f], &Bl[cur ^ 1][bd[f]]); bp[f] += 32; }
    }
    half8 af[MI], bfr[4];
#pragma unroll
    for (int i = 0; i < MI; ++i) af[i] = *(const half8*)(&Al[cur][aoff[i]]);
#pragma unroll
    for (int j = 0; j < 4; ++j) bfr[j] = *(const half8*)(&Bl[cur][boff[j]]);
#pragma unroll
    for (int i = 0; i < MI; ++i)
#pragma unroll
      for (int j = 0; j < 4; ++j)
        acc[i][j] = __builtin_amdgcn_mfma_f32_16x16x32_f16(af[i], bfr[j], acc[i][j], 0, 0, 0);
    __syncthreads();
    cur ^= 1;
  }
#pragma unroll
  for (int i = 0; i < MI; ++i)
#pragma unroll
    for (int r = 0; r < 4; ++r) {
      int m = m0 + wr + i * 16 + lk * 4 + r;
#pragma unroll
      for (int j = 0; j < 4; ++j) {
        int n = n0 + wc + j * 16 + lr;
        float v = acc[i][j][r];
        if (EPI == 1) {
          ((short*)C)[(size_t)m * N + n] = f2h(v);
        } else if (EPI == 2) {
          v = 0.5f * v * (1.0f + erff(v * 0.70710678118654752f));
          ((short*)C)[(size_t)m * N + n] = f2h(v);
        } else {
          ((float*)C)[(size_t)m * N + n] = v + R[(size_t)m * N + n];
        }
      }
    }
}

// ------- logits GEMM: 128x128, 2-phase dbuf gload pipeline + XCD 1D grid ------
__global__ __launch_bounds__(256) void gemm_logits_g_kernel(
    const short* __restrict__ A, const short* __restrict__ BT,
    float* __restrict__ C, int M, int N, int K)
{
  int bid = blockIdx.x;
  int xcd = bid & 7, idx0 = bid >> 3;
  int mt = idx0 & 15, yt = (idx0 >> 4) + xcd * YPX;
  if (yt >= NTILES_V) return;
  int m0 = mt * 128, n0 = yt * 128;

  __shared__ short Al[2][128 * 32];
  __shared__ short Bl[2][128 * 32];
  int tid = threadIdx.x;
  int wave = tid >> 6, lane = tid & 63;
  int wr = (wave >> 1) * 64, wc = (wave & 1) * 64;
  int lr = lane & 15, lk = lane >> 4;
  f32x4 acc[4][4] = {};

  const short* ap[2]; int ad[2];
  const short* bp[2]; int bd[2];
#pragma unroll
  for (int f = 0; f < 2; ++f) {
    int idx = tid + f * 256;
    int row = idx >> 2, slot = idx & 3;
    ap[f] = A + (size_t)(m0 + row) * K + ((slot ^ (row & 3)) * 8);
    ad[f] = idx * 8;
    bp[f] = BT + (size_t)(n0 + row) * K + ((slot ^ (row & 3)) * 8);
    bd[f] = idx * 8;
  }
  int aoff[4], boff[4];
#pragma unroll
  for (int i = 0; i < 4; ++i) {
    int row = wr + i * 16 + lr;
    aoff[i] = row * 32 + ((lk ^ (row & 3)) * 8);
    int rowb = wc + i * 16 + lr;
    boff[i] = rowb * 32 + ((lk ^ (rowb & 3)) * 8);
  }

#pragma unroll
  for (int f = 0; f < 2; ++f) { gload16(ap[f], &Al[0][ad[f]]); ap[f] += 32; }
#pragma unroll
  for (int f = 0; f < 2; ++f) { gload16(bp[f], &Bl[0][bd[f]]); bp[f] += 32; }
  __syncthreads();

  const int nt = K >> 5;
  int cur = 0;
  for (int t = 0; t < nt; ++t) {
    if (t + 1 < nt) {
#pragma unroll
      for (int f = 0; f < 2; ++f) { gload16(ap[f], &Al[cur ^ 1][ad[f]]); ap[f] += 32; }
#pragma unroll
      for (int f = 0; f < 2; ++f) { gload16(bp[f], &Bl[cur ^ 1][bd[f]]); bp[f] += 32; }
    }
    half8 af[4], bfr[4];
#pragma unroll
    for (int i = 0; i < 4; ++i) af[i] = *(const half8*)(&Al[cur][aoff[i]]);
#pragma unroll
    for (int j = 0; j < 4; ++j) bfr[j] = *(const half8*)(&Bl[cur][boff[j]]);
#pragma unroll
    for (int i = 0; i < 4; ++i)
#pragma unroll
      for (int j = 0; j < 4; ++j)
        acc[i][j] = __builtin_amdgcn_mfma_f32_16x16x32_f16(af[i], bfr[j], acc[i][j], 0, 0, 0);
    __syncthreads();
    cur ^= 1;
  }
#pragma unroll
  for (int i = 0; i < 4; ++i)
#pragma unroll
    for (int r = 0; r < 4; ++r) {
      int m = m0 + wr + i * 16 + lk * 4 + r;
#pragma unroll
      for (int j = 0; j < 4; ++j) {
        int n = n0 + wc + j * 16 + lr;
        if (n < N) C[(size_t)m * N + n] = acc[i][j][r];
      }
    }
}

// ------- logits fallback: B fp32 [N][K] inline-cvt (when ws too small) -------
__global__ __launch_bounds__(256) void gemm_logits_f32b_kernel(
    const short* __restrict__ A, const float* __restrict__ BT,
    float* __restrict__ C, int M, int N, int K)
{
  __shared__ short Al[128 * RA];
  __shared__ short Bl[128 * RA];
  int tid = threadIdx.x;
  int wave = tid >> 6, lane = tid & 63;
  int wr = (wave >> 1) * 64, wc = (wave & 1) * 64;
  int lr = lane & 15, lk = lane >> 4;
  int m0 = blockIdx.y * 128, n0 = blockIdx.x * 128;
  f32x4 acc[4][4] = {};

  for (int k0 = 0; k0 < K; k0 += 32) {
    __syncthreads();
#pragma unroll
    for (int f = 0; f < 2; ++f) {
      int idx = tid + f * 256, row = idx >> 2, sub = idx & 3;
      uint4 v = *(const uint4*)(A + (size_t)(m0 + row) * K + k0 + sub * 8);
      *(uint4*)(Al + row * RA + sub * 8) = v;
    }
#pragma unroll
    for (int f = 0; f < 4; ++f) {
      int idx = tid + f * 256, row = idx >> 3, qq = idx & 7;
      int gn = n0 + row;
      float4 v = make_float4(0.f, 0.f, 0.f, 0.f);
      if (gn < N) v = *(const float4*)(BT + (size_t)gn * K + k0 + qq * 4);
      *(short4*)(Bl + row * RA + qq * 4) =
          make_short4(f2h(v.x), f2h(v.y), f2h(v.z), f2h(v.w));
    }
    __syncthreads();
    half8 af[4], bfr[4];
#pragma unroll
    for (int i = 0; i < 4; ++i)
      af[i] = *(const half8*)(Al + (wr + i * 16 + lr) * RA + lk * 8);
#pragma unroll
    for (int j = 0; j < 4; ++j)
      bfr[j] = *(const half8*)(Bl + (wc + j * 16 + lr) * RA + lk * 8);
#pragma unroll
    for (int i = 0; i < 4; ++i)
#pragma unroll
      for (int j = 0; j < 4; ++j)
        acc[i][j] = __builtin_amdgcn_mfma_f32_16x16x32_f16(af[i], bfr[j], acc[i][j], 0, 0, 0);
  }
#pragma unroll
  for (int i = 0; i < 4; ++i)
#pragma unroll
    for (int r = 0; r < 4; ++r) {
      int m = m0 + wr + i * 16 + lk * 4 + r;
#pragma unroll
      for (int j = 0; j < 4; ++j) {
        int n = n0 + wc + j * 16 + lr;
        if (n < N) C[(size_t)m * N + n] = acc[i][j][r];
      }
    }
}

// ---------------- indexer scores + exact stable top-k -> bitmask ----------------
// 512 threads: halves the serial iterations of score loop and bitonic stages.
__device__ __forceinline__ unsigned int ford(float f) {
  unsigned int u = __float_as_uint(f);
  return (u & 0x80000000u) ? ~u : (u | 0x80000000u);
}

__global__ __launch_bounds__(512) void idx_topk_kernel(
    const float* __restrict__ Hx, unsigned int* __restrict__ MASK)
{
  int bq = blockIdx.x;
  int q = bq & (S_LEN - 1);
  int b = bq >> 10;
  int tid = threadIdx.x;
  int n = q + 1;
  if (n <= TOPK_N) {
    if (tid < 32) {
      int full = n >> 5, rem = n & 31;
      unsigned int w = 0u;
      if (tid < full) w = 0xFFFFFFFFu;
      else if (tid == full && rem) w = (1u << rem) - 1u;
      MASK[(size_t)bq * 32 + tid] = w;
    }
    return;
  }
  __shared__ float qi_s[HI_N * DI_N];
  __shared__ float wt_s[HI_N];
  __shared__ float sc[S_LEN];
  __shared__ unsigned long long keys[S_LEN];
  __shared__ unsigned int mw[32];
  if (tid < HI_N * DI_N) qi_s[tid] = Hx[(size_t)bq * IDX_LD + COL_QI + tid];
  if (tid < HI_N) wt_s[tid] = Hx[(size_t)bq * IDX_LD + COL_WT + tid];
  __syncthreads();
  for (int k = tid; k < n; k += 512) {
    const float* kr = Hx + (size_t)(b * S_LEN + k) * IDX_LD + COL_KI;
    float d0 = 0.f, d1 = 0.f, d2 = 0.f, d3 = 0.f;
#pragma unroll
    for (int d = 0; d < DI_N; ++d) {
      float kv = kr[d];
      d0 = fmaf(qi_s[d], kv, d0);
      d1 = fmaf(qi_s[64 + d], kv, d1);
      d2 = fmaf(qi_s[128 + d], kv, d2);
      d3 = fmaf(qi_s[192 + d], kv, d3);
    }
    sc[k] = wt_s[0] * fmaxf(d0, 0.f) + wt_s[1] * fmaxf(d1, 0.f)
          + wt_s[2] * fmaxf(d2, 0.f) + wt_s[3] * fmaxf(d3, 0.f);
  }
  __syncthreads();
  for (int i = tid; i < S_LEN; i += 512) {
    unsigned long long kk = 0ull;
    if (i < n) kk = ((unsigned long long)ford(sc[i]) << 32) | (unsigned int)(S_LEN - 1 - i);
    keys[i] = kk;
  }
  __syncthreads();
  for (int size = 2; size <= S_LEN; size <<= 1) {
    for (int stride = size >> 1; stride > 0; stride >>= 1) {
      {
        int t = tid;  // exactly S_LEN/2 = 512 pairs per stage
        int j = t & (stride - 1);
        int lo = ((t ^ j) << 1) | j;
        int hi = lo | stride;
        unsigned long long a = keys[lo], c = keys[hi];
        bool desc = ((lo & size) == 0);
        bool sw = desc ? (a < c) : (a > c);
        if (sw) { keys[lo] = c; keys[hi] = a; }
      }
      __syncthreads();
    }
  }
  if (tid < 32) mw[tid] = 0u;
  __syncthreads();
  if (tid < TOPK_N) {
    int k = S_LEN - 1 - (int)(keys[tid] & 0xFFFFFFFFull);
    atomicOr(&mw[k >> 5], 1u << (k & 31));
  }
  __syncthreads();
  if (tid < 32) MASK[(size_t)bq * 32 + tid] = mw[tid];
}

// ------- masked-dense flash attention: x32 QK^T + x16 PV, 1-barrier pipeline ---
__global__ __launch_bounds__(256) void attn_mfma_kernel(
    const short* __restrict__ QKV, const unsigned int* __restrict__ MASK,
    short* __restrict__ O /* [BSROWS][D] fp16 */)
{
  __shared__ short Kl[2][64 * 64];
  __shared__ short Vtl[2][64 * 68];
  int i = blockIdx.x;
  int p = i >> 5;
  int qt = (p < 8) ? p : 23 - p;
  int h = (i >> 1) & 15;
  int b = i & 1;
  int tid = threadIdx.x;
  int w = tid >> 6, l = tid & 63;
  int lq = l & 15, g = l >> 4;
  int q0 = qt * 64;
  const short* Kb = QKV + (size_t)b * S_LEN * QKV_LD + 1024 + h * DHD;
  const short* Vb = QKV + (size_t)b * S_LEN * QKV_LD + 2048 + h * DHD;
  int vu = tid >> 1, vhalf = tid & 1, vkg = vu >> 3, vdg = vu & 7;
  const int mrow = w * 16 + lq;
  const unsigned int* mp = MASK + (size_t)(b * S_LEN + q0 + mrow) * 32;

  half8 qf[2];
  {
    const short* qrow = QKV + ((size_t)(b * S_LEN + q0 + mrow)) * QKV_LD + h * DHD;
    qf[0] = *(const half8*)(qrow + g * 8);
    qf[1] = *(const half8*)(qrow + 32 + g * 8);
  }
  unsigned int mw0 = mp[0], mw1 = mp[1];
  {
#pragma unroll
    for (int i2 = 0; i2 < 2; ++i2) {
      int idx = tid + i2 * 256;
      int row = idx >> 3, sub = idx & 7;
      gload16(Kb + (size_t)row * QKV_LD + (size_t)((sub ^ (row & 7)) * 8), &Kl[0][idx * 8]);
    }
    int krow = vkg * 4 + vhalf * 2;
    uint4 v0 = *(const uint4*)(Vb + (size_t)krow * QKV_LD + vdg * 8);
    uint4 v1 = *(const uint4*)(Vb + (size_t)(krow + 1) * QKV_LD + vdg * 8);
    const short* s0 = (const short*)&v0;
    const short* s1 = (const short*)&v1;
#pragma unroll
    for (int j = 0; j < 8; ++j)
      *(short2*)(&Vtl[0][(vdg * 8 + j) * 68 + vkg * 4 + vhalf * 2]) = make_short2(s0[j], s1[j]);
  }
  __syncthreads();

  f32x4 acc_o[4] = {};
  float m_run = -1.0e30f, l_run = 0.f;
  int cur = 0;

  for (int kt = 0; kt <= qt; ++kt) {
    bool more = kt < qt;
    uint4 v0, v1;
    unsigned int nmw0 = 0u, nmw1 = 0u;
    if (more) {
#pragma unroll
      for (int i2 = 0; i2 < 2; ++i2) {
        int idx = tid + i2 * 256;
        int row = idx >> 3, sub = idx & 7;
        gload16(Kb + (size_t)((kt + 1) * 64 + row) * QKV_LD + (size_t)((sub ^ (row & 7)) * 8),
                &Kl[cur ^ 1][idx * 8]);
      }
      int krow = (kt + 1) * 64 + vkg * 4 + vhalf * 2;
      v0 = *(const uint4*)(Vb + (size_t)krow * QKV_LD + vdg * 8);
      v1 = *(const uint4*)(Vb + (size_t)(krow + 1) * QKV_LD + vdg * 8);
      nmw0 = mp[2 * (kt + 1)];
      nmw1 = mp[2 * (kt + 1) + 1];
    }
    f32x4 s[4] = {};
    __builtin_amdgcn_s_setprio(1);
#pragma unroll
    for (int ks = 0; ks < 4; ++ks) {
      half8 kf0 = *(const half8*)(&Kl[cur][(ks * 16 + lq) * 64 + ((g ^ (lq & 7)) * 8)]);
      half8 kf1 = *(const half8*)(&Kl[cur][(ks * 16 + lq) * 64 + (((4 + g) ^ (lq & 7)) * 8)]);
      s[ks] = __builtin_amdgcn_mfma_f32_16x16x32_f16(kf0, qf[0], s[ks], 0, 0, 0);
      s[ks] = __builtin_amdgcn_mfma_f32_16x16x32_f16(kf1, qf[1], s[ks], 0, 0, 0);
    }
    __builtin_amdgcn_s_setprio(0);
    float mx = NEGF;
#pragma unroll
    for (int ks = 0; ks < 4; ++ks) {
      unsigned int mwv = (ks < 2) ? mw0 : mw1;
      int bb = (ks & 1) * 16 + g * 4;
#pragma unroll
      for (int r = 0; r < 4; ++r) {
        float sv = ((mwv >> (bb + r)) & 1u) ? s[ks][r] * 0.125f : NEGF;
        s[ks][r] = sv;
        mx = fmaxf(mx, sv);
      }
    }
    mx = fmaxf(mx, __shfl_xor(mx, 16));
    mx = fmaxf(mx, __shfl_xor(mx, 32));
    float m_new = fmaxf(m_run, mx);
    float scale = __expf(m_run - m_new);
    float lsum = 0.f;
    half4v pf[4];
#pragma unroll
    for (int ks = 0; ks < 4; ++ks) {
      half4v t;
#pragma unroll
      for (int r = 0; r < 4; ++r) {
        float pp = __expf(s[ks][r] - m_new);
        lsum += pp;
        t[r] = (_Float16)pp;
      }
      pf[ks] = t;
    }
    lsum += __shfl_xor(lsum, 16);
    lsum += __shfl_xor(lsum, 32);
    l_run = l_run * scale + lsum;
    m_run = m_new;
    float sc[4];
#pragma unroll
    for (int r = 0; r < 4; ++r) sc[r] = __shfl(scale, g * 4 + r);
    __builtin_amdgcn_s_setprio(1);
#pragma unroll
    for (int dt = 0; dt < 4; ++dt) {
      f32x4 a = acc_o[dt];
      a[0] *= sc[0]; a[1] *= sc[1]; a[2] *= sc[2]; a[3] *= sc[3];
#pragma unroll
      for (int ks = 0; ks < 4; ++ks) {
        half4v vf = *(const half4v*)(&Vtl[cur][(dt * 16 + lq) * 68 + ks * 16 + g * 4]);
        a = MFMA16F(pf[ks], vf, a);
      }
      acc_o[dt] = a;
    }
    __builtin_amdgcn_s_setprio(0);
    if (more) {
      const short* s0 = (const short*)&v0;
      const short* s1 = (const short*)&v1;
#pragma unroll
      for (int j = 0; j < 8; ++j)
        *(short2*)(&Vtl[cur ^ 1][(vdg * 8 + j) * 68 + vkg * 4 + vhalf * 2]) = make_short2(s0[j], s1[j]);
      mw0 = nmw0;
      mw1 = nmw1;
    }
    __syncthreads();
    cur ^= 1;
  }
  float linv[4];
#pragma unroll
  for (int r = 0; r < 4; ++r) linv[r] = 1.0f / __shfl(l_run, g * 4 + r);
#pragma unroll
  for (int dt = 0; dt < 4; ++dt)
#pragma unroll
    for (int r = 0; r < 4; ++r) {
      int q = q0 + w * 16 + g * 4 + r;
      float o = acc_o[dt][r] * linv[r];
      O[(size_t)(b * S_LEN + q) * D_DIM + h * DHD + dt * 16 + lq] = f2h(o);
    }
}

// ---------------- host orchestration ----------------
extern "C" void kernel_launch(void* const* d_in, const int* in_sizes, int n_in,
                              void* d_out, int out_size, void* d_ws, size_t ws_size,
                              hipStream_t stream) {
  (void)in_sizes; (void)n_in; (void)out_size;
  const int*   tokens  = (const int*)d_in[0];
  const float* embed_w = (const float*)d_in[1];
  const float* pos_w   = (const float*)d_in[2];
  const float* wq      = (const float*)d_in[3];
  const float* wk      = (const float*)d_in[4];
  const float* wv      = (const float*)d_in[5];
  const float* wo      = (const float*)d_in[6];
  const float* iqw     = (const float*)d_in[7];
  const float* ikw     = (const float*)d_in[8];
  const float* iww     = (const float*)d_in[9];
  const float* w1      = (const float*)d_in[10];
  const float* w2      = (const float*)d_in[11];
  const float* n1      = (const float*)d_in[12];
  const float* n2      = (const float*)d_in[13];
  const float* nf      = (const float*)d_in[14];
  float* logits = (float*)d_out;

  // ws: Hh (logits A, 4 MB) + Eh (fp16 embed padded to VPAD rows, 103 MB)
  short* Hh = (short*)d_ws;
  size_t need_eh = ((size_t)BSROWS * D_DIM + (size_t)VPAD * D_DIM) * 2;
  bool use_eh = ws_size >= need_eh;
  short* Eh = Hh + (size_t)BSROWS * D_DIM;

  // d_out scratch (all dead before logits GEMM writes)
  char* base = (char*)d_out;
  size_t off = (size_t)BSROWS * D_DIM * 4;
  float* X = logits;
  float* Hx = (float*)(base + off);    off += (size_t)BSROWS * IDX_LD * 4;
  short* QKVh = (short*)(base + off);  off += (size_t)BSROWS * QKV_LD * 2;
  short* Hsp = (short*)(base + off);   off += (size_t)2 * BSROWS * D_DIM * 2;
  short* AOh = (short*)(base + off);   off += (size_t)BSROWS * D_DIM * 2;
  short* FFh = (short*)(base + off);   off += (size_t)BSROWS * FF_DIM * 2;
  unsigned int* MASKb = (unsigned int*)(base + off); off += (size_t)BSROWS * 32 * 4;
  short* BTqkvA = (short*)(base + off); off += (size_t)NL * QKV_LD * D_DIM * 2;
  short* BTidxA = (short*)(base + off); off += (size_t)NL * 2 * IDX_LD * D_DIM * 2;
  short* BTwoA = (short*)(base + off);  off += (size_t)NL * D_DIM * D_DIM * 2;
  short* BTw1A = (short*)(base + off);  off += (size_t)NL * FF_DIM * D_DIM * 2;
  short* BTw2A = (short*)(base + off);  off += (size_t)NL * FF_DIM * D_DIM * 2;

  const size_t plH  = (size_t)BSROWS * D_DIM;
  const size_t plIx = (size_t)IDX_LD * D_DIM;

  hipLaunchKernelGGL(embed_kernel, dim3(BSROWS), dim3(256), 0, stream,
                     tokens, embed_w, pos_w, X);
  if (use_eh)
    hipLaunchKernelGGL(cvt_embed_kernel, dim3(8192), dim3(256), 0, stream, embed_w, Eh);

  // all-layer weight packs (5 dispatches total, float4-vectorized)
  hipLaunchKernelGGL(pack_qkv_all_kernel, dim3(QKV_LD / 128, 32, NL), dim3(256), 0, stream,
                     wq, wk, wv, BTqkvA);
  hipLaunchKernelGGL(pack_idx_all_kernel, dim3(IDX_LD / 32, 32, NL), dim3(32, 8), 0, stream,
                     iqw, ikw, iww, BTidxA);
  hipLaunchKernelGGL(packT_all_kernel, dim3(D_DIM / 128, 32, NL), dim3(256), 0, stream,
                     wo, BTwoA, D_DIM, D_DIM);
  hipLaunchKernelGGL(packT_all_kernel, dim3(FF_DIM / 128, 32, NL), dim3(256), 0, stream,
                     w1, BTw1A, D_DIM, FF_DIM);
  hipLaunchKernelGGL(packT_all_kernel, dim3(D_DIM / 128, FF_DIM / 32, NL), dim3(256), 0, stream,
                     w2, BTw2A, FF_DIM, D_DIM);

  for (int l = 0; l < NL; ++l) {
    short* BTqkv = BTqkvA + (size_t)l * QKV_LD * D_DIM;
    short* BTidx = BTidxA + (size_t)l * 2 * IDX_LD * D_DIM;
    short* BTwo  = BTwoA + (size_t)l * D_DIM * D_DIM;
    short* BTw1  = BTw1A + (size_t)l * FF_DIM * D_DIM;
    short* BTw2  = BTw2A + (size_t)l * FF_DIM * D_DIM;

    hipLaunchKernelGGL(rmsnorm_split_kernel, dim3(BSROWS), dim3(256), 0, stream,
                       X, n1 + (size_t)l * D_DIM, Hsp);
    hipLaunchKernelGGL((gemm_g_kernel<64, 1>), dim3(QKV_LD / 128, 32), dim3(256), 0, stream,
                       Hsp, BTqkv, nullptr, QKVh, BSROWS, QKV_LD, D_DIM);
    hipLaunchKernelGGL((gemm_split_kernel<32>), dim3(IDX_LD / 128, 64), dim3(256), 0, stream,
                       Hsp, plH, BTidx, plIx, Hx, BSROWS, IDX_LD, D_DIM);
    hipLaunchKernelGGL(idx_topk_kernel, dim3(BSROWS), dim3(512), 0, stream, Hx, MASKb);
    hipLaunchKernelGGL(attn_mfma_kernel, dim3(512), dim3(256), 0, stream,
                       QKVh, MASKb, AOh);
    hipLaunchKernelGGL((gemm_g_kernel<32, 3>), dim3(8, 64), dim3(256), 0, stream,
                       AOh, BTwo, X, X, BSROWS, D_DIM, D_DIM);
    hipLaunchKernelGGL(rmsnorm_h_kernel, dim3(BSROWS), dim3(256), 0, stream,
                       X, n2 + (size_t)l * D_DIM, Hsp);
    hipLaunchKernelGGL((gemm_g_kernel<64, 2>), dim3(FF_DIM / 128, 32), dim3(256), 0, stream,
                       Hsp, BTw1, nullptr, FFh, BSROWS, FF_DIM, D_DIM);
    hipLaunchKernelGGL((gemm_g_kernel<32, 3>), dim3(8, 64), dim3(256), 0, stream,
                       FFh, BTw2, X, X, BSROWS, D_DIM, FF_DIM);
  }

  hipLaunchKernelGGL(rmsnorm_h_kernel, dim3(BSROWS), dim3(256), 0, stream, X, nf, Hh);
  if (use_eh) {
    hipLaunchKernelGGL(gemm_logits_g_kernel, dim3(8 * YPX * 16), dim3(256), 0, stream,
                       Hh, Eh, logits, BSROWS, VOCAB, D_DIM);
  } else {
    hipLaunchKernelGGL(gemm_logits_f32b_kernel, dim3((VOCAB + 127) / 128, 16), dim3(256), 0, stream,
                       Hh, embed_w, logits, BSROWS, VOCAB, D_DIM);
  }
}